// Round 17
// baseline (158.599 us; speedup 1.0000x reference)
//
#include <hip/hip_runtime.h>
#include <cstdint>
#include <cstddef>

// ---------------------------------------------------------------------------
// RNN_No_FFNN: h_t = sigmoid(hidden@U_w.T + U_b + line@W_w.T + W_b)
//              pred = h_t@V_w.T + V_b ; out0 = segmented log_softmax(pred)
// B=8192, H=2048, D=104.  Outputs: [pred_logsoft (8192*104) | h_t (8192*2048)] f32.
// R17 = R16 + gemm2 FUSED into gemm1 via partial-pred atomics:
//   pred = sum over col-bands of h_tile @ Vw_slice.T -> each gemm1 block
//   computes its [128x104] partial with a short bf16-MFMA pass (h_bf tile +
//   Vw slice in the dead LDS halves, chunk-major conflict-free layout) and
//   atomicAdds into predP f32 (device-scope, cross-XCD safe). Deletes the
//   32MB ht_bf write + 32MB gemm2 read + gemm2 kernel. prep zeroes predP.
//   Final tiny softmax kernel: predP + Vb -> segmented log-softmax -> outLS.
// gemm1 K-loop/staging byte-identical to R16 (117.7us, 3x reproduced).
// ---------------------------------------------------------------------------

typedef __bf16 bf16x8 __attribute__((ext_vector_type(8)));
typedef float  f32x4  __attribute__((ext_vector_type(4)));
typedef float  f32x16 __attribute__((ext_vector_type(16)));
typedef int    i32x4  __attribute__((ext_vector_type(4)));
typedef int    i32x8  __attribute__((ext_vector_type(8)));
typedef unsigned short ushort8 __attribute__((ext_vector_type(8)));
typedef unsigned char  uchar8  __attribute__((ext_vector_type(8)));
typedef float  float4v __attribute__((ext_vector_type(4)));

#define BB 8192
#define HH 2048
#define DD 104

static __device__ __forceinline__ unsigned short f2bf(float f) {
  unsigned u = __float_as_uint(f);
  unsigned r = (u + 0x7FFFu + ((u >> 16) & 1u)) >> 16;  // RNE
  return (unsigned short)r;
}

// f32 -> OCP e4m3fn, RNE, saturate to 448. Subnormal grid 2^-9 via float2int_rn.
static __device__ __forceinline__ unsigned char f2fp8(float x) {
  unsigned u = __float_as_uint(x);
  unsigned s = (u >> 24) & 0x80u;
  float ax = fabsf(x);
  ax = fminf(ax, 448.0f);
  unsigned code;
  if (ax >= 0.015625f) {                    // normal: exp >= -6
    unsigned b = __float_as_uint(ax);
    unsigned lsb = (b >> 20) & 1u;
    b += 0x0007FFFFu + lsb;                 // RNE at mantissa bit 20
    unsigned e = (b >> 23) & 0xFFu;         // 121..135 after clamp
    code = ((e - 120u) << 3) | ((b >> 20) & 7u);
  } else {                                  // subnormal: step 2^-9 (carry into normal ok)
    code = (unsigned)__float2int_rn(ax * 512.0f);
  }
  return (unsigned char)(s | code);
}

// async global->LDS, 16B per lane (dest = wave-uniform base + lane*16: linear)
#define GLD_LDS(g, l)                                                          \
  __builtin_amdgcn_global_load_lds(                                            \
      (__attribute__((address_space(1))) void*)(g),                            \
      (__attribute__((address_space(3))) void*)(l), 16, 0, 0)

#define MEMFENCE asm volatile("" ::: "memory")
#define MFMA16(a, b, c) __builtin_amdgcn_mfma_f32_16x16x32_bf16((a), (b), (c), 0, 0, 0)

// ---------------------------------------------------------------------------
// prep_kernel = conv_fp8 (blocks 0..10239) + pad_mixed (10240..16383)
//             + predP zeroing (16384..17215).
// ---------------------------------------------------------------------------
__global__ __launch_bounds__(256) void prep_kernel(
    const float* __restrict__ hidden, const float* __restrict__ Uw,
    const float* __restrict__ line, const float* __restrict__ Ww,
    const float* __restrict__ Vw,
    unsigned char* __restrict__ out_h, unsigned char* __restrict__ out_u,
    unsigned char* __restrict__ line8, unsigned char* __restrict__ Ww8,
    unsigned short* __restrict__ Vw_bf, float* __restrict__ predP) {
  const int bid = blockIdx.x;
  if (bid < 10240) {
    long long i = ((long long)bid * blockDim.x + threadIdx.x) * 8;
    const float* src; unsigned char* dst; long long off;
    if (i < (long long)BB * HH) { src = hidden; dst = out_h; off = i; }
    else { src = Uw; dst = out_u; off = i - (long long)BB * HH; }
    float4v a = *(const float4v*)(src + off);
    float4v b = *(const float4v*)(src + off + 4);
    uchar8 o;
    o[0]=f2fp8(a[0]); o[1]=f2fp8(a[1]); o[2]=f2fp8(a[2]); o[3]=f2fp8(a[3]);
    o[4]=f2fp8(b[0]); o[5]=f2fp8(b[1]); o[6]=f2fp8(b[2]); o[7]=f2fp8(b[3]);
    *(uchar8*)(dst + off) = o;
  } else if (bid < 16384) {
    int i = (bid - 10240) * blockDim.x + threadIdx.x;
    const int N1 = BB * 128;          // 1048576
    const int N2 = N1 + HH * 128;     // 1310720
    if (i < N1) {
      int r = i >> 7, c = i & 127;
      line8[i] = (c < DD) ? f2fp8(line[r * DD + c]) : (unsigned char)0;
    } else if (i < N2) {
      int j = i - N1; int r = j >> 7, c = j & 127;
      Ww8[j] = (c < DD) ? f2fp8(Ww[r * DD + c]) : (unsigned char)0;
    } else {
      int j = i - N2; int r = j >> 11, c = j & 2047;
      Vw_bf[j] = (r < DD) ? f2bf(Vw[r * 2048 + c]) : (unsigned short)0;
    }
  } else {
    // zero predP: 8192*104 = 851968 f32 = 212992 float4 = 832 blocks x 256
    int i = (bid - 16384) * 256 + threadIdx.x;
    float4v z = {0.0f, 0.0f, 0.0f, 0.0f};
    ((float4v*)predP)[i] = z;
  }
}

// ---------------------------------------------------------------------------
// GEMM1 (R16 K-loop exact) + fused partial-pred pass.
// K-loop LDS: A bufs [0,32768), B bufs [32768,65536); per buf 32KB =
// [pair:4][row:128][32B].  After the K-loop both halves are dead:
//   A half <- h_bf tile, chunk-major [g:16][row:128][8 bf16] (16B entries)
//   B half <- Vw slice   [g:16][row:128][8 bf16] staged via GLD_LDS.
// bf16 MFMA pass: per wave 64x64 out, 4 k-steps; frag reads 16B at
// g*2048 + row*16 -> bank-base (row*4)&31 = conflict-free signature.
// Partial pred atomicAdd'ed to predP (f32, device scope).
// ---------------------------------------------------------------------------
__global__ __launch_bounds__(256, 2) void gemm1_kernel(
    const unsigned char* __restrict__ A8,   // hidden fp8 [8192][2048]
    const unsigned char* __restrict__ L8,   // line fp8 [8192][128] (zero-pad)
    const unsigned char* __restrict__ U8w,  // U_w fp8 [2048][2048]
    const unsigned char* __restrict__ W8w,  // W_w fp8 [2048][128] (zero-pad)
    const unsigned short* __restrict__ VwB, // Vw_bf [128][2048]
    const float* __restrict__ Ub, const float* __restrict__ Wb,
    float* __restrict__ outH, float* __restrict__ predP) {
  __shared__ __attribute__((aligned(32))) unsigned char smem[65536];  // 64 KB
  const int t = threadIdx.x;
  const int l = t & 63;
  const int wid = t >> 6;
  const int wr = wid >> 1, wc = wid & 1;    // 2 x 2 waves, 64x64 out each

  // bijective XCD-chunked swizzle: 1024 wgs, 8 XCDs, 128/chunk
  const int bid = blockIdx.x;
  const int wg = (bid & 7) * 128 + (bid >> 3);
  const int brow = (wg >> 4) * 128;   // 64 M tiles
  const int bcol = (wg & 15) * 128;   // 16 N tiles

  const int lr = l & 31;              // fragment row within 32-row band
  const int lc = l >> 5;              // k-half-chunk select

  // staging addressing
  const int sr = t >> 1, sh = (t & 1) * 16;
  const unsigned char* pA = A8 + (size_t)(brow + sr) * 2048 + sh;
  const unsigned char* pL = L8 + (size_t)(brow + sr) * 128 + sh;
  const unsigned char* pU = U8w + (size_t)(bcol + sr) * 2048 + sh;
  const unsigned char* pW = W8w + (size_t)(bcol + sr) * 128 + sh;
  unsigned char* dA = smem + t * 16;            // + buf*16384 + q*4096
  unsigned char* dB = smem + 32768 + t * 16;

  f32x16 acc[2][2] = {};

  auto stage = [&](int kt, int buf) {
    const int kb = kt * 128;
    unsigned char* da = dA + buf * 16384;
    unsigned char* db = dB + buf * 16384;
    if (kb < 2048) {
#pragma unroll
      for (int q = 0; q < 4; ++q) {
        GLD_LDS(pA + kb + q * 32, da + q * 4096);
        GLD_LDS(pU + kb + q * 32, db + q * 4096);
      }
    } else {  // K-tail: line/W_w pads (row stride 128, col base 0)
#pragma unroll
      for (int q = 0; q < 4; ++q) {
        GLD_LDS(pL + q * 32, da + q * 4096);
        GLD_LDS(pW + q * 32, db + q * 4096);
      }
    }
  };

  // prologue: stage K-tile 0 into buf 0
  stage(0, 0);
  asm volatile("s_waitcnt vmcnt(0)" ::: "memory");
  MEMFENCE; __builtin_amdgcn_s_barrier(); MEMFENCE;

  // K = 2176 = 17 tiles of 128 (2048 hidden/U_w + 128 line/W_w concat)
  for (int kt = 0; kt < 17; ++kt) {
    const int cur = kt & 1;
    if (kt < 16) {
      stage(kt + 1, cur ^ 1);
      asm volatile("s_waitcnt vmcnt(8)" ::: "memory");  // tile kt fully landed
    } else {
      asm volatile("s_waitcnt vmcnt(0)" ::: "memory");
    }
    const unsigned char* Ab = smem + cur * 16384;
    const unsigned char* Bb = smem + 32768 + cur * 16384;
#pragma unroll
    for (int s = 0; s < 2; ++s) {           // two K=64 MFMA steps
      const int pr = (s * 2 + lc) * 4096;
      i32x8 af[2], bfv[2];
#pragma unroll
      for (int m = 0; m < 2; ++m)
        af[m] = *(const i32x8*)(Ab + pr + (wr * 64 + m * 32 + lr) * 32);
#pragma unroll
      for (int n = 0; n < 2; ++n)
        bfv[n] = *(const i32x8*)(Bb + pr + (wc * 64 + n * 32 + lr) * 32);
      __builtin_amdgcn_s_setprio(1);
#pragma unroll
      for (int m = 0; m < 2; ++m)
#pragma unroll
        for (int n = 0; n < 2; ++n)
          acc[m][n] = __builtin_amdgcn_mfma_scale_f32_32x32x64_f8f6f4(
              af[m], bfv[n], acc[m][n], 0 /*fp8 A*/, 0 /*fp8 B*/,
              0, 0x7F7F7F7F /*unit scales A*/, 0, 0x7F7F7F7F /*unit scales B*/);
      __builtin_amdgcn_s_setprio(0);
    }
    MEMFENCE; __builtin_amdgcn_s_barrier(); MEMFENCE;  // reads done -> buf reusable
  }

  // ---- fused partial-pred pass ----
  // 1) stage Vw slice [128 pred-rows][k=bcol..bcol+128) bf16 -> B half,
  //    chunk-major: chunk = q*2 + (t>>7) covers k [chunk*8, +8); row = t&127.
  {
    const unsigned short* pV = VwB + (size_t)(t & 127) * 2048 + bcol + (t >> 7) * 8;
    unsigned char* dV = smem + 32768 + t * 16;
#pragma unroll
    for (int q = 0; q < 8; ++q)
      GLD_LDS(pV + q * 16, dV + q * 4096);
  }
  // 2) epilogue: +bias, sigmoid, write f32 h_t, and h_bf -> A half chunk-major.
  //    C/D 32x32: n = l&31 (lcol), m-row = (reg&3)+8*(reg>>2)+4*lc.
#pragma unroll
  for (int nf = 0; nf < 2; ++nf) {
    const int lcol = wc * 64 + nf * 32 + lr;
    const int col = bcol + lcol;
    const float bias = Ub[col] + Wb[col];
    unsigned short* hcol = (unsigned short*)smem + (lcol >> 3) * 1024 + (lcol & 7);
#pragma unroll
    for (int mf = 0; mf < 2; ++mf) {
#pragma unroll
      for (int reg = 0; reg < 16; ++reg) {
        const int lrow = wr * 64 + mf * 32 + (reg & 3) + 8 * (reg >> 2) + 4 * lc;
        const float v = acc[mf][nf][reg] + bias;
        const float h = 1.0f / (1.0f + __expf(-v));
        outH[(size_t)(brow + lrow) * HH + col] = h;
        hcol[lrow * 8] = f2bf(h);   // byte: (lcol>>3)*2048 + lrow*16 + (lcol&7)*2
      }
    }
  }
  __syncthreads();  // drains Vw GLDs (vmcnt) + h_bf ds_writes (lgkm)

  // 3) bf16 MFMA pass: partial[128 rows][128 pred-cols] = h_bf @ VwSlice^T
  {
    const int frow = l & 15, fk = l >> 4;
    f32x4 acc2[4][4] = {};
#pragma unroll
    for (int ks = 0; ks < 4; ++ks) {
      const int g = ks * 4 + fk;
      bf16x8 av[4], bv[4];
#pragma unroll
      for (int mi = 0; mi < 4; ++mi)
        av[mi] = *(const bf16x8*)(smem + g * 2048 + (wr * 64 + mi * 16 + frow) * 16);
#pragma unroll
      for (int ni = 0; ni < 4; ++ni)
        bv[ni] = *(const bf16x8*)(smem + 32768 + g * 2048 + (wc * 64 + ni * 16 + frow) * 16);
#pragma unroll
      for (int mi = 0; mi < 4; ++mi)
#pragma unroll
        for (int ni = 0; ni < 4; ++ni)
          acc2[mi][ni] = MFMA16(av[mi], bv[ni], acc2[mi][ni]);
    }
    // 4) atomic accumulation into predP (device-scope f32, cross-XCD safe)
#pragma unroll
    for (int ni = 0; ni < 4; ++ni) {
      const int d = wc * 64 + ni * 16 + frow;
      if (d < DD) {
#pragma unroll
        for (int mi = 0; mi < 4; ++mi) {
          const int r0 = brow + wr * 64 + mi * 16 + fk * 4;
#pragma unroll
          for (int j = 0; j < 4; ++j)
            atomicAdd(&predP[(size_t)(r0 + j) * DD + d], acc2[mi][ni][j]);
        }
      }
    }
  }
}

// ---------------------------------------------------------------------------
// softmax_kernel: outLS = segmented log-softmax(predP + Vb). One thread/row.
// ---------------------------------------------------------------------------
__global__ __launch_bounds__(256) void softmax_kernel(
    const float* __restrict__ predP, const float* __restrict__ Vb,
    float* __restrict__ outLS) {
  const int r = blockIdx.x * 256 + threadIdx.x;   // grid 32 x 256 = 8192 rows
  const float* p = predP + (size_t)r * DD;
  float* o = outLS + (size_t)r * DD;
  const int segb[11] = {0, 13, 26, 39, 48, 52, 65, 78, 91, 100, 104};
  for (int s = 0; s < 10; ++s) {
    const int a = segb[s], b = segb[s + 1];
    float mx = -3.0e38f;
    for (int c = a; c < b; ++c) mx = fmaxf(mx, p[c] + Vb[c]);
    float sum = 0.0f;
    for (int c = a; c < b; ++c) sum += __expf(p[c] + Vb[c] - mx);
    const float ls = __logf(sum) + mx;
    for (int c = a; c < b; ++c) o[c] = p[c] + Vb[c] - ls;
  }
}

// ---------------------------------------------------------------------------
// Launch
// ---------------------------------------------------------------------------
extern "C" void kernel_launch(void* const* d_in, const int* in_sizes, int n_in,
                              void* d_out, int out_size, void* d_ws, size_t ws_size,
                              hipStream_t stream) {
  (void)in_sizes; (void)n_in; (void)out_size; (void)ws_size;
  const float* line   = (const float*)d_in[0];
  const float* hidden = (const float*)d_in[1];
  const float* Uw     = (const float*)d_in[2];
  const float* Ub     = (const float*)d_in[3];
  const float* Ww     = (const float*)d_in[4];
  const float* Wb     = (const float*)d_in[5];
  const float* Vw     = (const float*)d_in[6];
  const float* Vb     = (const float*)d_in[7];

  char* ws = (char*)d_ws;
  unsigned char* hid8    = (unsigned char*)(ws);               // 16,777,216
  unsigned char* U8w     = (unsigned char*)(ws + 16777216);    //  4,194,304
  unsigned char* line8   = (unsigned char*)(ws + 20971520);    //  1,048,576
  unsigned char* Ww8     = (unsigned char*)(ws + 22020096);    //    262,144
  unsigned short* Vw_bf  = (unsigned short*)(ws + 22282240);   //    524,288
  float* predP           = (float*)(ws + 22806528);            //  3,407,872

  float* outLS = (float*)d_out;                    // [8192][104]
  float* outH  = (float*)d_out + (size_t)BB * DD;  // [8192][2048]

  // conv (10240) + pad (6144) + predP zero (832) = 17216 blocks
  prep_kernel<<<17216, 256, 0, stream>>>(hidden, Uw, line, Ww, Vw,
                                         hid8, U8w, line8, Ww8, Vw_bf, predP);
  gemm1_kernel<<<1024, 256, 0, stream>>>(hid8, line8, U8w, Ww8, Vw_bf, Ub, Wb,
                                         outH, predP);
  softmax_kernel<<<32, 256, 0, stream>>>(predP, Vb, outLS);
}

// Round 18
// 116.409 us; speedup vs baseline: 1.3624x; 1.3624x over previous
//
#include <hip/hip_runtime.h>
#include <cstdint>
#include <cstddef>

// ---------------------------------------------------------------------------
// RNN_No_FFNN: h_t = sigmoid(hidden@U_w.T + U_b + line@W_w.T + W_b)
//              pred = h_t@V_w.T + V_b ; out0 = segmented log_softmax(pred)
// B=8192, H=2048, D=104.  Outputs: [pred_logsoft (8192*104) | h_t (8192*2048)] f32.
// R18 = R16 VERBATIM (best measured: 117.7us; config reproduced 3x at
//   117.7-118.0). R17's atomic fusion regressed to 158.6 (write-side LDS
//   bank conflicts + 13.6M device atomics) -> reverted per pre-commitment.
// gemm1: MX-fp8 e4m3 (unit scales) mfma_scale_f32_32x32x64_f8f6f4.
//   128x128 tile, 256 thr (2x2 waves, 64x64/wave), BK=128, 2x32KB LDS dbuf,
//   k-pair-major LDS layout [pair:4][row:128][32B], counted vmcnt(8).
// gemm2: bf16 16x16x32 + fused segmented log-softmax (64-row/128-block).
// prep: conv_fp8 + pad merged (one launch).
// ---------------------------------------------------------------------------

typedef __bf16 bf16x8 __attribute__((ext_vector_type(8)));
typedef float  f32x4  __attribute__((ext_vector_type(4)));
typedef float  f32x16 __attribute__((ext_vector_type(16)));
typedef int    i32x4  __attribute__((ext_vector_type(4)));
typedef int    i32x8  __attribute__((ext_vector_type(8)));
typedef unsigned short ushort8 __attribute__((ext_vector_type(8)));
typedef unsigned char  uchar8  __attribute__((ext_vector_type(8)));
typedef float  float4v __attribute__((ext_vector_type(4)));

#define BB 8192
#define HH 2048
#define DD 104

static __device__ __forceinline__ unsigned short f2bf(float f) {
  unsigned u = __float_as_uint(f);
  unsigned r = (u + 0x7FFFu + ((u >> 16) & 1u)) >> 16;  // RNE
  return (unsigned short)r;
}

// f32 -> OCP e4m3fn, RNE, saturate to 448. Subnormal grid 2^-9 via float2int_rn.
static __device__ __forceinline__ unsigned char f2fp8(float x) {
  unsigned u = __float_as_uint(x);
  unsigned s = (u >> 24) & 0x80u;
  float ax = fabsf(x);
  ax = fminf(ax, 448.0f);
  unsigned code;
  if (ax >= 0.015625f) {                    // normal: exp >= -6
    unsigned b = __float_as_uint(ax);
    unsigned lsb = (b >> 20) & 1u;
    b += 0x0007FFFFu + lsb;                 // RNE at mantissa bit 20
    unsigned e = (b >> 23) & 0xFFu;         // 121..135 after clamp
    code = ((e - 120u) << 3) | ((b >> 20) & 7u);
  } else {                                  // subnormal: step 2^-9 (carry into normal ok)
    code = (unsigned)__float2int_rn(ax * 512.0f);
  }
  return (unsigned char)(s | code);
}

// async global->LDS, 16B per lane (dest = wave-uniform base + lane*16: linear)
#define GLD_LDS(g, l)                                                          \
  __builtin_amdgcn_global_load_lds(                                            \
      (__attribute__((address_space(1))) void*)(g),                            \
      (__attribute__((address_space(3))) void*)(l), 16, 0, 0)

#define MEMFENCE asm volatile("" ::: "memory")
#define MFMA16(a, b, c) __builtin_amdgcn_mfma_f32_16x16x32_bf16((a), (b), (c), 0, 0, 0)

// ---------------------------------------------------------------------------
// prep_kernel = conv_fp8 (blocks 0..10239) + pad_mixed (blocks 10240..16383)
// ---------------------------------------------------------------------------
__global__ __launch_bounds__(256) void prep_kernel(
    const float* __restrict__ hidden, const float* __restrict__ Uw,
    const float* __restrict__ line, const float* __restrict__ Ww,
    const float* __restrict__ Vw,
    unsigned char* __restrict__ out_h, unsigned char* __restrict__ out_u,
    unsigned char* __restrict__ line8, unsigned char* __restrict__ Ww8,
    unsigned short* __restrict__ Vw_bf) {
  const int bid = blockIdx.x;
  if (bid < 10240) {
    // conv part: hidden (16777216) then U_w (4194304), f32 -> fp8, 8/thread
    long long i = ((long long)bid * blockDim.x + threadIdx.x) * 8;
    const float* src; unsigned char* dst; long long off;
    if (i < (long long)BB * HH) { src = hidden; dst = out_h; off = i; }
    else { src = Uw; dst = out_u; off = i - (long long)BB * HH; }
    float4v a = *(const float4v*)(src + off);
    float4v b = *(const float4v*)(src + off + 4);
    uchar8 o;
    o[0]=f2fp8(a[0]); o[1]=f2fp8(a[1]); o[2]=f2fp8(a[2]); o[3]=f2fp8(a[3]);
    o[4]=f2fp8(b[0]); o[5]=f2fp8(b[1]); o[6]=f2fp8(b[2]); o[7]=f2fp8(b[3]);
    *(uchar8*)(dst + off) = o;
  } else {
    // pad part: line->line8[8192,128], Ww->Ww8[2048,128], Vw->Vw_bf[128,2048]
    int i = (bid - 10240) * blockDim.x + threadIdx.x;
    const int N1 = BB * 128;          // 1048576
    const int N2 = N1 + HH * 128;     // 1310720
    if (i < N1) {
      int r = i >> 7, c = i & 127;
      line8[i] = (c < DD) ? f2fp8(line[r * DD + c]) : (unsigned char)0;
    } else if (i < N2) {
      int j = i - N1; int r = j >> 7, c = j & 127;
      Ww8[j] = (c < DD) ? f2fp8(Ww[r * DD + c]) : (unsigned char)0;
    } else {
      int j = i - N2; int r = j >> 11, c = j & 2047;
      Vw_bf[j] = (r < DD) ? f2bf(Vw[r * 2048 + c]) : (unsigned short)0;
    }
  }
}

// ---------------------------------------------------------------------------
// GEMM1. LDS: A bufs [0,32768), B bufs [32768,65536); per buf 32KB =
// [pair:4][row:128][32B], pair = 32B k-chunk of the 128-K tile.
// LDS[pair][row] = G[row][kb + pair*32 .. +32].
// Staging: thread t -> (row = t>>1, half = t&1): source
// G[row][kb + q*32 + half*16], dest = q*4096 + t*16 (linear per wave).
// Fragment read: lane l (lr=l&31, lc=l>>5), k-step s: ONE contiguous 32B at
// (s*2+lc)*4096 + row*32.
// Same k-bijection for A and B -> dot product exact regardless of HW k-order.
// C/D 32x32: n = l&31, m = (reg&3)+8*(reg>>2)+4*(l>>5).
// ---------------------------------------------------------------------------
__global__ __launch_bounds__(256, 2) void gemm1_kernel(
    const unsigned char* __restrict__ A8,   // hidden fp8 [8192][2048]
    const unsigned char* __restrict__ L8,   // line fp8 [8192][128] (zero-pad)
    const unsigned char* __restrict__ U8w,  // U_w fp8 [2048][2048]
    const unsigned char* __restrict__ W8w,  // W_w fp8 [2048][128] (zero-pad)
    const float* __restrict__ Ub, const float* __restrict__ Wb,
    float* __restrict__ outH, unsigned short* __restrict__ outHbf) {
  __shared__ __attribute__((aligned(32))) unsigned char smem[65536];  // 64 KB
  const int t = threadIdx.x;
  const int l = t & 63;
  const int wid = t >> 6;
  const int wr = wid >> 1, wc = wid & 1;    // 2 x 2 waves, 64x64 out each

  // bijective XCD-chunked swizzle: 1024 wgs, 8 XCDs, 128/chunk
  const int bid = blockIdx.x;
  const int wg = (bid & 7) * 128 + (bid >> 3);
  const int brow = (wg >> 4) * 128;   // 64 M tiles
  const int bcol = (wg & 15) * 128;   // 16 N tiles

  const int lr = l & 31;              // fragment row within 32-row band
  const int lc = l >> 5;              // k-half-chunk select

  // staging addressing
  const int sr = t >> 1, sh = (t & 1) * 16;
  const unsigned char* pA = A8 + (size_t)(brow + sr) * 2048 + sh;
  const unsigned char* pL = L8 + (size_t)(brow + sr) * 128 + sh;
  const unsigned char* pU = U8w + (size_t)(bcol + sr) * 2048 + sh;
  const unsigned char* pW = W8w + (size_t)(bcol + sr) * 128 + sh;
  unsigned char* dA = smem + t * 16;            // + buf*16384 + q*4096
  unsigned char* dB = smem + 32768 + t * 16;

  f32x16 acc[2][2] = {};

  auto stage = [&](int kt, int buf) {
    const int kb = kt * 128;
    unsigned char* da = dA + buf * 16384;
    unsigned char* db = dB + buf * 16384;
    if (kb < 2048) {
#pragma unroll
      for (int q = 0; q < 4; ++q) {
        GLD_LDS(pA + kb + q * 32, da + q * 4096);
        GLD_LDS(pU + kb + q * 32, db + q * 4096);
      }
    } else {  // K-tail: line/W_w pads (row stride 128, col base 0)
#pragma unroll
      for (int q = 0; q < 4; ++q) {
        GLD_LDS(pL + q * 32, da + q * 4096);
        GLD_LDS(pW + q * 32, db + q * 4096);
      }
    }
  };

  // prologue: stage K-tile 0 into buf 0
  stage(0, 0);
  asm volatile("s_waitcnt vmcnt(0)" ::: "memory");
  MEMFENCE; __builtin_amdgcn_s_barrier(); MEMFENCE;

  // K = 2176 = 17 tiles of 128 (2048 hidden/U_w + 128 line/W_w concat)
  for (int kt = 0; kt < 17; ++kt) {
    const int cur = kt & 1;
    if (kt < 16) {
      stage(kt + 1, cur ^ 1);
      asm volatile("s_waitcnt vmcnt(8)" ::: "memory");  // tile kt fully landed
    } else {
      asm volatile("s_waitcnt vmcnt(0)" ::: "memory");
    }
    const unsigned char* Ab = smem + cur * 16384;
    const unsigned char* Bb = smem + 32768 + cur * 16384;
#pragma unroll
    for (int s = 0; s < 2; ++s) {           // two K=64 MFMA steps
      const int pr = (s * 2 + lc) * 4096;
      i32x8 af[2], bfv[2];
#pragma unroll
      for (int m = 0; m < 2; ++m)
        af[m] = *(const i32x8*)(Ab + pr + (wr * 64 + m * 32 + lr) * 32);
#pragma unroll
      for (int n = 0; n < 2; ++n)
        bfv[n] = *(const i32x8*)(Bb + pr + (wc * 64 + n * 32 + lr) * 32);
      __builtin_amdgcn_s_setprio(1);
#pragma unroll
      for (int m = 0; m < 2; ++m)
#pragma unroll
        for (int n = 0; n < 2; ++n)
          acc[m][n] = __builtin_amdgcn_mfma_scale_f32_32x32x64_f8f6f4(
              af[m], bfv[n], acc[m][n], 0 /*fp8 A*/, 0 /*fp8 B*/,
              0, 0x7F7F7F7F /*unit scales A*/, 0, 0x7F7F7F7F /*unit scales B*/);
      __builtin_amdgcn_s_setprio(0);
    }
    MEMFENCE; __builtin_amdgcn_s_barrier(); MEMFENCE;  // reads done -> buf reusable
  }

  // epilogue: +bias, sigmoid, dual write.
  // C/D 32x32: n = l&31, m = (reg&3) + 8*(reg>>2) + 4*(l>>5)
#pragma unroll
  for (int nf = 0; nf < 2; ++nf) {
    const int col = bcol + wc * 64 + nf * 32 + lr;
    const float bias = Ub[col] + Wb[col];
#pragma unroll
    for (int mf = 0; mf < 2; ++mf) {
#pragma unroll
      for (int reg = 0; reg < 16; ++reg) {
        const int row = brow + wr * 64 + mf * 32 + (reg & 3) + 8 * (reg >> 2) + 4 * lc;
        const float v = acc[mf][nf][reg] + bias;
        const float h = 1.0f / (1.0f + __expf(-v));
        const size_t idx = (size_t)row * HH + col;
        outH[idx] = h;
        outHbf[idx] = f2bf(h);
      }
    }
  }
}

// ---------------------------------------------------------------------------
// GEMM2 (bf16): pred = h_t@V_w.T + V_b + fused seg log-softmax
// ---------------------------------------------------------------------------
template <int NM, int NN>
static __device__ __forceinline__ void mfma_step(
    const unsigned short* sA, const unsigned short* sB, int arow0, int brow0,
    int frow, int fk, f32x4 (&acc)[NM][NN]) {
  bf16x8 af[NM], bfr[NN];
#pragma unroll
  for (int m = 0; m < NM; ++m)
    af[m] = *(const bf16x8*)(sA + (arow0 + m * 16 + frow) * 32 + fk);
#pragma unroll
  for (int n = 0; n < NN; ++n)
    bfr[n] = *(const bf16x8*)(sB + (brow0 + n * 16 + frow) * 32 + fk);
#pragma unroll
  for (int m = 0; m < NM; ++m)
#pragma unroll
    for (int n = 0; n < NN; ++n)
      acc[m][n] = MFMA16(af[m], bfr[n], acc[m][n]);
}

__global__ __launch_bounds__(256, 2) void gemm2_kernel(
    const unsigned short* __restrict__ A,   // h_t bf16 [8192][2048]
    const unsigned short* __restrict__ Bm,  // Vw_bf [128][2048]
    const float* __restrict__ Vb,
    float* __restrict__ outLS) {            // [8192][104] f32
  __shared__ unsigned short sA[64 * 32];
  __shared__ unsigned short sB[128 * 32];
  __shared__ float pred[64 * 105];
  const int t = threadIdx.x;
  const int l = t & 63;
  const int wid = t >> 6, wr = wid >> 1, wc = wid & 1;
  const int brow = blockIdx.x * 64;
  const int srow = t >> 2, scg = t & 3;
  const int frow = l & 15, fk = (l >> 4) * 8;

  const unsigned short* gA = A + (size_t)(brow + srow) * HH + scg * 8;
  const unsigned short* gB = Bm + (size_t)srow * HH + scg * 8;
  unsigned short* lA = sA + t * 8;
  unsigned short* lB = sB + t * 8;

  f32x4 acc[2][4] = {};
  for (int ks = 0; ks < 64; ++ks) {
    __syncthreads();
    GLD_LDS(gA, lA);
    GLD_LDS(gB, lB);
    GLD_LDS(gB + 64 * HH, lB + 64 * 32);
    gA += 32; gB += 32;
    __syncthreads();
    mfma_step<2, 4>(sA, sB, wr * 32, wc * 64, frow, fk, acc);
  }

#pragma unroll
  for (int n = 0; n < 4; ++n) {
    const int col = wc * 64 + n * 16 + frow;
    if (col < DD) {
      const float vb = Vb[col];
#pragma unroll
      for (int m = 0; m < 2; ++m) {
        const int r0 = wr * 32 + m * 16 + (l >> 4) * 4;
#pragma unroll
        for (int j = 0; j < 4; ++j)
          pred[(r0 + j) * 105 + col] = acc[m][n][j] + vb;
      }
    }
  }
  __syncthreads();

  if (t < 64) {
    const int segb[11] = {0, 13, 26, 39, 48, 52, 65, 78, 91, 100, 104};
    const float* p = pred + t * 105;
    float* o = outLS + (size_t)(brow + t) * DD;
    for (int s = 0; s < 10; ++s) {
      const int a = segb[s], b = segb[s + 1];
      float mx = -3.0e38f;
      for (int c = a; c < b; ++c) mx = fmaxf(mx, p[c]);
      float sum = 0.0f;
      for (int c = a; c < b; ++c) sum += __expf(p[c] - mx);
      const float ls = __logf(sum) + mx;
      for (int c = a; c < b; ++c) o[c] = p[c] - ls;
    }
  }
}

// ---------------------------------------------------------------------------
// Launch
// ---------------------------------------------------------------------------
extern "C" void kernel_launch(void* const* d_in, const int* in_sizes, int n_in,
                              void* d_out, int out_size, void* d_ws, size_t ws_size,
                              hipStream_t stream) {
  (void)in_sizes; (void)n_in; (void)out_size; (void)ws_size;
  const float* line   = (const float*)d_in[0];
  const float* hidden = (const float*)d_in[1];
  const float* Uw     = (const float*)d_in[2];
  const float* Ub     = (const float*)d_in[3];
  const float* Ww     = (const float*)d_in[4];
  const float* Wb     = (const float*)d_in[5];
  const float* Vw     = (const float*)d_in[6];
  const float* Vb     = (const float*)d_in[7];

  char* ws = (char*)d_ws;
  unsigned char* hid8    = (unsigned char*)(ws);               // 16,777,216
  unsigned char* U8w     = (unsigned char*)(ws + 16777216);    //  4,194,304
  unsigned char* line8   = (unsigned char*)(ws + 20971520);    //  1,048,576
  unsigned char* Ww8     = (unsigned char*)(ws + 22020096);    //    262,144
  unsigned short* Vw_bf  = (unsigned short*)(ws + 22282240);   //    524,288
  unsigned short* ht_bf  = (unsigned short*)(ws + 22806528);   // 33,554,432

  float* outLS = (float*)d_out;                    // [8192][104]
  float* outH  = (float*)d_out + (size_t)BB * DD;  // [8192][2048]

  // merged conv (10240 blocks) + pad (6144 blocks)
  prep_kernel<<<16384, 256, 0, stream>>>(hidden, Uw, line, Ww, Vw,
                                         hid8, U8w, line8, Ww8, Vw_bf);
  gemm1_kernel<<<1024, 256, 0, stream>>>(hid8, line8, U8w, Ww8, Ub, Wb,
                                         outH, ht_bf);
  gemm2_kernel<<<128, 256, 0, stream>>>(ht_bf, Vw_bf, Vb, outLS);
}